// Round 3
// baseline (3552.283 us; speedup 1.0000x reference)
//
#include <hip/hip_runtime.h>
#include <hip/hip_bf16.h>
#include <stdint.h>
#include <stddef.h>

// Problem constants (from reference): T=2048, B=16, D=1024. ALL I/O = float32.
#define T_DIM 2048
#define B_DIM 16
#define D_DIM 1024
#define BD    (B_DIM * D_DIM)          // 16384 state elements
#define TBD   ((size_t)T_DIM * BD)     // 33554432
#define NC    128                      // lookback chunks over T
#define TCH   (T_DIM / NC)             // 16 steps per chunk

using bf16 = __hip_bfloat16;
typedef __attribute__((ext_vector_type(8))) short short8;   // 8 x bf16 = 4 VGPRs
typedef __attribute__((ext_vector_type(4))) float f32x4;
typedef __attribute__((ext_vector_type(4))) unsigned int u32x4;

// f32 -> bf16 bits, round-to-nearest-even (finite inputs).
__device__ __forceinline__ unsigned f2bf(float f) {
    unsigned u = __float_as_uint(f);
    return (u + 0x7FFFu + ((u >> 16) & 1u)) >> 16;
}

// Agent-scope atomics for cross-XCD publish/consume (per-XCD L2 non-coherent).
__device__ __forceinline__ void st_rel_u32(unsigned int* p, unsigned int v) {
    __hip_atomic_store(p, v, __ATOMIC_RELEASE, __HIP_MEMORY_SCOPE_AGENT);
}
__device__ __forceinline__ unsigned int ld_acq_u32(const unsigned int* p) {
    return __hip_atomic_load(p, __ATOMIC_ACQUIRE, __HIP_MEMORY_SCOPE_AGENT);
}
__device__ __forceinline__ void st_rlx_f32(float* p, float v) {
    __hip_atomic_store(p, v, __ATOMIC_RELAXED, __HIP_MEMORY_SCOPE_AGENT);
}
__device__ __forceinline__ float ld_rlx_f32(const float* p) {
    return __hip_atomic_load(p, __ATOMIC_RELAXED, __HIP_MEMORY_SCOPE_AGENT);
}

// ---------------------------------------------------------------------------
// f32 buffer -> bf16 buffer (for MFMA operands). 8 elems/thread.
// ---------------------------------------------------------------------------
__global__ __launch_bounds__(256) void cvt_f32_bf16(
    const float* __restrict__ src, short* __restrict__ dst, int n8)
{
    int i = blockIdx.x * 256 + threadIdx.x;
    if (i >= n8) return;
    const float* p = src + (size_t)i * 8;
    f32x4 a = *(const f32x4*)p;
    f32x4 b = *(const f32x4*)(p + 4);
    short8 r;
    r[0] = (short)f2bf(a[0]); r[1] = (short)f2bf(a[1]);
    r[2] = (short)f2bf(a[2]); r[3] = (short)f2bf(a[3]);
    r[4] = (short)f2bf(b[0]); r[5] = (short)f2bf(b[1]);
    r[6] = (short)f2bf(b[2]); r[7] = (short)f2bf(b[3]);
    *(short8*)(dst + (size_t)i * 8) = r;
}

// Zero a u32 region (flags + ticket) each launch; graph-capturable.
__global__ __launch_bounds__(256) void zero_u32(unsigned int* __restrict__ p, int n4)
{
    int i = blockIdx.x * 256 + threadIdx.x;
    if (i < n4) ((u32x4*)p)[i] = (u32x4){0u, 0u, 0u, 0u};
}

// ---------------------------------------------------------------------------
// async global->LDS, 16B per lane. LDS dest is wave-uniform base + lane*16.
// ---------------------------------------------------------------------------
typedef __attribute__((address_space(1))) void gvoid;
typedef __attribute__((address_space(3))) void lvoid;
__device__ __forceinline__ void gload_lds16(const short* g, short* l) {
    __builtin_amdgcn_global_load_lds((gvoid*)g, (lvoid*)l, 16, 0, 0);
}

// ---------------------------------------------------------------------------
// Fused K/V projection GEMM, m97 structure: 128x128 tile, BK=32, LDS
// double-buffered via global_load_lds width=16, ds_read_b128 fragments,
// one __syncthreads per K-step. XCD-chunked block swizzle (T1): FETCH_SIZE
// measured 531 -> 99 MB, dur 265 -> 227 us (R1).
//   pre[m][n] = sum_d x[m][d]*W[n][d]  (NT, both row-major K-fast)
//   z==0: k = sigmoid(pre+b_k); z==1: v = tanh(pre+b_v)
// ---------------------------------------------------------------------------
__global__ __launch_bounds__(256, 4) void gemm_kv_bf16(
    const short* __restrict__ xb,
    const short* __restrict__ Wkb, const float* __restrict__ bk,
    const short* __restrict__ Wvb, const float* __restrict__ bv,
    float* __restrict__ kout, float* __restrict__ vout)
{
    __shared__ short sA[2][128 * 32];   // 8KB per buffer
    __shared__ short sB[2][128 * 32];

    const int tid  = threadIdx.x;
    const int lane = tid & 63;
    const int wave = tid >> 6;
    const int wm   = wave & 1;
    const int wn   = wave >> 1;
    const int quad = lane >> 4;
    const int l15  = lane & 15;

    // XCD-chunked swizzle: nwg=4096, 8 XCDs, 512 tiles/XCD (bijective).
    const int lin = blockIdx.x + (blockIdx.y << 3) + (blockIdx.z << 11);
    const int swz = ((lin & 7) << 9) | (lin >> 3);
    const bool is_k = (swz >> 11) == 0;
    const int blkm = (swz >> 3) & 255;   // 0..255
    const int blkn = swz & 7;            // 0..7

    const short* W    = is_k ? Wkb : Wvb;
    const float* bias = is_k ? bk : bv;
    float*       outp = is_k ? kout : vout;

    const int m0 = blkm * 128;
    const int n0 = blkn * 128;

    const int srow = wave * 16 + (lane >> 2);        // 0..63 within half
    const int skof = (lane & 3) * 8;                 // shorts
    const short* ga = xb + (size_t)(m0 + srow) * D_DIM + skof;
    const short* gb = W  + (size_t)(n0 + srow) * D_DIM + skof;
    const int lofs = wave * 512;                     // wave*16 rows * 32 shorts

    auto STAGE = [&](int buf, int ks) {
        const size_t ko = (size_t)ks * 32;
        gload_lds16(ga + ko,                        &sA[buf][lofs]);
        gload_lds16(ga + ko + (size_t)64 * D_DIM,   &sA[buf][2048 + lofs]);
        gload_lds16(gb + ko,                        &sB[buf][lofs]);
        gload_lds16(gb + ko + (size_t)64 * D_DIM,   &sB[buf][2048 + lofs]);
    };

    f32x4 acc[4][4] = {};

    STAGE(0, 0);
    int cur = 0;
    for (int ks = 0; ks < D_DIM / 32; ++ks) {
        __syncthreads();
        if (ks + 1 < D_DIM / 32) STAGE(cur ^ 1, ks + 1);

        const short* lA = sA[cur];
        const short* lB = sB[cur];
        short8 a[4], b[4];
#pragma unroll
        for (int mt = 0; mt < 4; ++mt)
            a[mt] = *(const short8*)&lA[(wm * 64 + mt * 16 + l15) * 32 + quad * 8];
#pragma unroll
        for (int nt = 0; nt < 4; ++nt)
            b[nt] = *(const short8*)&lB[(wn * 64 + nt * 16 + l15) * 32 + quad * 8];
#pragma unroll
        for (int mt = 0; mt < 4; ++mt)
#pragma unroll
            for (int nt = 0; nt < 4; ++nt)
                acc[mt][nt] = __builtin_amdgcn_mfma_f32_16x16x32_bf16(
                    a[mt], b[nt], acc[mt][nt], 0, 0, 0);
        cur ^= 1;
    }

    const int gm0 = blkm * 128 + wm * 64 + quad * 4;
    const int gn  = blkn * 128 + wn * 64 + l15;
#pragma unroll
    for (int nt = 0; nt < 4; ++nt) {
        const int n = gn + nt * 16;
        const float bs = bias[n];
#pragma unroll
        for (int mt = 0; mt < 4; ++mt) {
            const int m = gm0 + mt * 16;
#pragma unroll
            for (int r = 0; r < 4; ++r) {
                float pre = acc[mt][nt][r] + bs;
                pre = fminf(20.f, fmaxf(-20.f, pre));
                float o;
                if (is_k) o = 1.f / (1.f + __expf(-pre));                // sigmoid
                else      o = 2.f / (1.f + __expf(-2.f * pre)) - 1.f;    // tanh
                outp[(size_t)(m + r) * D_DIM + n] = o;
            }
        }
    }
}

// ---------------------------------------------------------------------------
// Fallback GEMM when ws too small: load f32 operands, convert in-kernel.
// ---------------------------------------------------------------------------
__device__ __forceinline__ short8 load_cvt8(const float* p) {
    f32x4 a = *(const f32x4*)p;
    f32x4 b = *(const f32x4*)(p + 4);
    short8 r;
    r[0] = (short)f2bf(a[0]); r[1] = (short)f2bf(a[1]);
    r[2] = (short)f2bf(a[2]); r[3] = (short)f2bf(a[3]);
    r[4] = (short)f2bf(b[0]); r[5] = (short)f2bf(b[1]);
    r[6] = (short)f2bf(b[2]); r[7] = (short)f2bf(b[3]);
    return r;
}

__global__ __launch_bounds__(256) void gemm_kv_f32src(
    const float* __restrict__ x,
    const float* __restrict__ Wk, const float* __restrict__ bk,
    const float* __restrict__ Wv, const float* __restrict__ bv,
    float* __restrict__ kout, float* __restrict__ vout)
{
    const int tid  = threadIdx.x;
    const int lane = tid & 63;
    const int wave = tid >> 6;
    const int wm   = wave & 1;
    const int wn   = wave >> 1;
    const int quad = lane >> 4;
    const int l15  = lane & 15;

    const int blkn = blockIdx.x;
    const int blkm = blockIdx.y;
    const bool is_k = (blockIdx.z == 0);

    const float* W    = is_k ? Wk : Wv;
    const float* bias = is_k ? bk : bv;
    float*       outp = is_k ? kout : vout;

    const int m0 = blkm * 128 + wm * 64;
    const int n0 = blkn * 128 + wn * 64;

    const float* ap = x + (size_t)(m0 + l15) * D_DIM + quad * 8;
    const float* bp = W + (size_t)(n0 + l15) * D_DIM + quad * 8;

    f32x4 acc[4][4] = {};

    for (int ks = 0; ks < D_DIM / 32; ++ks) {
        short8 a[4], b[4];
#pragma unroll
        for (int mt = 0; mt < 4; ++mt)
            a[mt] = load_cvt8(ap + (size_t)mt * 16 * D_DIM + ks * 32);
#pragma unroll
        for (int nt = 0; nt < 4; ++nt)
            b[nt] = load_cvt8(bp + (size_t)nt * 16 * D_DIM + ks * 32);
#pragma unroll
        for (int mt = 0; mt < 4; ++mt)
#pragma unroll
            for (int nt = 0; nt < 4; ++nt)
                acc[mt][nt] = __builtin_amdgcn_mfma_f32_16x16x32_bf16(
                    a[mt], b[nt], acc[mt][nt], 0, 0, 0);
    }

    const int gm0 = blkm * 128 + wm * 64 + quad * 4;
    const int gn  = blkn * 128 + wn * 64 + l15;
#pragma unroll
    for (int nt = 0; nt < 4; ++nt) {
        const int n = gn + nt * 16;
        const float bs = bias[n];
#pragma unroll
        for (int mt = 0; mt < 4; ++mt) {
            const int m = gm0 + mt * 16;
#pragma unroll
            for (int r = 0; r < 4; ++r) {
                float pre = acc[mt][nt][r] + bs;
                pre = fminf(20.f, fmaxf(-20.f, pre));
                float o;
                if (is_k) o = 1.f / (1.f + __expf(-pre));
                else      o = 2.f / (1.f + __expf(-2.f * pre)) - 1.f;
                outp[(size_t)(m + r) * D_DIM + n] = o;
            }
        }
    }
}

// ---------------------------------------------------------------------------
// Single-pass decoupled-lookback scan of h_t = (1-k_t) h_{t-1} + k_t v_t.
// One block = (chunk c of TCH=16 steps, 256-channel slice). k/v stay in
// registers: one read of k/v, one write of h/out (no phase-A re-read).
//
// Deadlock-free under undefined dispatch order: blocks grab a TICKET via
// atomicAdd at start; ticket t -> c = t>>6. A block with ticket t only waits
// on chunks c' < c, whose tickets are strictly smaller, i.e. were grabbed by
// blocks that already STARTED executing. Workgroups are never preempted, so
// predecessors always make progress (induction) -> no deadlock.
//
// Cross-XCD correctness: per-channel flag (0=none,1=aggregate,2=inclusive)
// written by exactly one lane with agent-scope release; consumers use
// agent-scope acquire on the flag, then agent-scope relaxed payload loads
// (payload was stored before the release in the SAME publishing thread).
// Lookback decision is made per-wave uniform via __ballot (mixed 1/2 flags
// degrade to the aggregate path, which is always valid once flag>=1).
//
// In-place aliasing (kw==outp, vw==hsec+BD): each block reads only its own
// chunk's (t,bd) slots and later writes exactly those slots from the same
// thread -> read-before-write within thread, disjoint across blocks.
// ---------------------------------------------------------------------------
__global__ __launch_bounds__(256) void scan_lookback(
    const float* kw, const float* vw, const float* __restrict__ h0,
    float* outp, float* hsec,
    unsigned int* __restrict__ ticket,
    unsigned int* __restrict__ flags,      // [NC*BD]
    float* __restrict__ Apub,              // [NC*BD]
    float* __restrict__ Bpub,              // [NC*BD]
    float* __restrict__ Hpub)              // [NC*BD]
{
    __shared__ int s_ticket;
    const int tid = threadIdx.x;
    if (tid == 0) s_ticket = (int)atomicAdd(ticket, 1u);
    __syncthreads();
    const int tk    = s_ticket;
    const int c     = tk >> 6;           // 0..NC-1 (early tickets -> low c)
    const int slice = tk & 63;           // 0..63
    const int bd    = slice * 256 + tid; // 0..BD-1

    const size_t base = (size_t)c * TCH * BD + bd;
    const float* kp = kw + base;
    const float* vp = vw + base;

    float kk[TCH], vv[TCH];
#pragma unroll
    for (int j = 0; j < TCH; ++j) {
        kk[j] = kp[(size_t)j * BD];
        vv[j] = vp[(size_t)j * BD];
    }

    // Local chunk transform: h_out = A*h_in + Bv.
    float A = 1.f, Bv = 0.f;
#pragma unroll
    for (int j = 0; j < TCH; ++j) {
        const float a = 1.f - kk[j];
        A  = A * a;
        Bv = a * Bv + kk[j] * vv[j];
    }

    const size_t pub = (size_t)c * BD + bd;
    float hstart;
    if (c == 0) {
        hstart = h0[bd];
        hsec[bd] = hstart;                               // h[0] = h0
        st_rlx_f32(&Hpub[pub], A * hstart + Bv);
        st_rel_u32(&flags[pub], 2u);
    } else {
        // Publish aggregate immediately so successors can compose past us.
        st_rlx_f32(&Apub[pub], A);
        st_rlx_f32(&Bpub[pub], Bv);
        st_rel_u32(&flags[pub], 1u);

        // Lookback: h_start = aR * P_j + bR, (aR,bR) composes chunks j+1..c-1.
        float aR = 1.f, bR = 0.f;
        int j = c - 1;
        for (;;) {
            const size_t pj = (size_t)j * BD + bd;
            unsigned int f = ld_acq_u32(&flags[pj]);
            while (__ballot(f == 0u) != 0ull) {
                __builtin_amdgcn_s_sleep(4);
                f = ld_acq_u32(&flags[pj]);
            }
            if (__ballot(f != 2u) == 0ull) {             // whole wave inclusive
                hstart = aR * ld_rlx_f32(&Hpub[pj]) + bR;
                break;
            }
            const float Aj = ld_rlx_f32(&Apub[pj]);      // valid once flag>=1
            const float Bj = ld_rlx_f32(&Bpub[pj]);
            bR = bR + aR * Bj;                            // old aR
            aR = aR * Aj;
            --j;                                          // chunk 0 is always 2
        }
        st_rlx_f32(&Hpub[pub], A * hstart + Bv);
        st_rel_u32(&flags[pub], 2u);
    }

    // Replay from registers; write h and out.
    float h = hstart;
    float* op = outp + base;
    float* hp = hsec + base + BD;
#pragma unroll
    for (int j = 0; j < TCH; ++j) {
        h = (1.f - kk[j]) * h + kk[j] * vv[j];
        hp[(size_t)j * BD] = h;
        const float sig = 1.f / (1.f + __expf(-h));
        op[(size_t)j * BD] = h * h * sig;
    }
}

// ---------------------------------------------------------------------------
// Fallback 3-phase chunked scan (kept for small-ws paths).
// ---------------------------------------------------------------------------
__global__ __launch_bounds__(256) void scan_phase_a(
    const float* kw, const float* vw,
    float* __restrict__ Aab, float* __restrict__ Bab, int tc)
{
    const int bd = blockIdx.x * 256 + threadIdx.x;
    const int c  = blockIdx.y;
    const float* kp = kw + (size_t)c * tc * BD + bd;
    const float* vp = vw + (size_t)c * tc * BD + bd;

    float A = 1.f, Bv = 0.f;
    for (int t0 = 0; t0 < tc; t0 += 16) {
        float kk[16], vv[16];
#pragma unroll
        for (int j = 0; j < 16; ++j) {
            kk[j] = kp[(size_t)(t0 + j) * BD];
            vv[j] = vp[(size_t)(t0 + j) * BD];
        }
#pragma unroll
        for (int j = 0; j < 16; ++j) {
            const float a = 1.f - kk[j];
            A  = A * a;
            Bv = a * Bv + kk[j] * vv[j];
        }
    }
    Aab[(size_t)c * BD + bd] = A;
    Bab[(size_t)c * BD + bd] = Bv;
}

__global__ __launch_bounds__(256) void scan_phase_b(
    const float* __restrict__ h0,
    const float* __restrict__ Aab, const float* __restrict__ Bab,
    float* __restrict__ Hinit, float* hsec, int nc)
{
    const int bd = blockIdx.x * 256 + threadIdx.x;
    float h = h0[bd];
    hsec[bd] = h;
    for (int c0 = 0; c0 < nc; c0 += 16) {
        float aa[16], bb[16];
#pragma unroll
        for (int j = 0; j < 16; ++j) {
            aa[j] = Aab[(size_t)(c0 + j) * BD + bd];
            bb[j] = Bab[(size_t)(c0 + j) * BD + bd];
        }
#pragma unroll
        for (int j = 0; j < 16; ++j) {
            Hinit[(size_t)(c0 + j) * BD + bd] = h;
            h = aa[j] * h + bb[j];
        }
    }
}

__global__ __launch_bounds__(256) void scan_phase_c(
    const float* kw, const float* vw, const float* __restrict__ Hinit,
    float* outp, float* hsec, int tc)
{
    const int bd = blockIdx.x * 256 + threadIdx.x;
    const int c  = blockIdx.y;
    float h = Hinit[(size_t)c * BD + bd];

    const size_t base = (size_t)c * tc * BD + bd;
    const float* kp = kw + base;
    const float* vp = vw + base;
    float* op = outp + base;
    float* hp = hsec + base + BD;

    float kk[16], vv[16];
#pragma unroll
    for (int j = 0; j < 16; ++j) {
        kk[j] = kp[(size_t)j * BD];
        vv[j] = vp[(size_t)j * BD];
    }
    for (int t0 = 0; t0 < tc; t0 += 16) {
        float kn[16], vn[16];
        if (t0 + 16 < tc) {
#pragma unroll
            for (int j = 0; j < 16; ++j) {
                kn[j] = kp[(size_t)(t0 + 16 + j) * BD];
                vn[j] = vp[(size_t)(t0 + 16 + j) * BD];
            }
        }
#pragma unroll
        for (int j = 0; j < 16; ++j) {
            h = (1.f - kk[j]) * h + kk[j] * vv[j];
            hp[(size_t)(t0 + j) * BD] = h;
            const float sig = 1.f / (1.f + __expf(-h));
            op[(size_t)(t0 + j) * BD] = h * h * sig;
        }
        if (t0 + 16 < tc) {
#pragma unroll
            for (int j = 0; j < 16; ++j) { kk[j] = kn[j]; vv[j] = vn[j]; }
        }
    }
}

// ---------------------------------------------------------------------------
// Fallback sequential scan (ws too small for any chunk buffers).
// ---------------------------------------------------------------------------
__global__ __launch_bounds__(64) void scan_kernel(
    const float* kw, const float* vw, const float* h0,
    float* outp, float* hsec)
{
    const int c = blockIdx.x * 64 + threadIdx.x;
    float h = h0[c];
    hsec[c] = h;

    const float* kp = kw + c;
    const float* vp = vw + c;
    float* op = outp + c;
    float* hp = hsec + BD + c;

    for (int t = 0; t < T_DIM; t += 8) {
        float kk[8], vv[8];
#pragma unroll
        for (int j = 0; j < 8; ++j) {
            kk[j] = kp[(size_t)(t + j) * BD];
            vv[j] = vp[(size_t)(t + j) * BD];
        }
#pragma unroll
        for (int j = 0; j < 8; ++j) {
            h = (1.f - kk[j]) * h + kk[j] * vv[j];
            hp[(size_t)(t + j) * BD] = h;
            const float sig = 1.f / (1.f + __expf(-h));
            op[(size_t)(t + j) * BD] = h * h * sig;
        }
    }
}

// ---------------------------------------------------------------------------
extern "C" void kernel_launch(void* const* d_in, const int* in_sizes, int n_in,
                              void* d_out, int out_size, void* d_ws, size_t ws_size,
                              hipStream_t stream)
{
    const float* x  = (const float*)d_in[0];   // [T,B,D]
    const float* h0 = (const float*)d_in[1];   // [B,D]
    const float* Wk = (const float*)d_in[2];   // [D,D]
    const float* bk = (const float*)d_in[3];   // [D]
    const float* Wv = (const float*)d_in[4];   // [D,D]
    const float* bv = (const float*)d_in[5];   // [D]

    float* outp = (float*)d_out;               // output section [T,B,D]
    float* hsec = outp + TBD;                  // h section [T+1,B,D]

    // k -> output section, v -> h[1:] section: element-exact in-place (safe,
    // see scan comments). No workspace needed for k/v themselves.
    float* kw = outp;
    float* vw = hsec + BD;

    const size_t bf16_bytes = (TBD + 2 * (size_t)D_DIM * D_DIM) * sizeof(short);
    // Lookback region: ticket(4B, padded to 256) + flags + A + B + H.
    const size_t lb_flags = (size_t)NC * BD * sizeof(unsigned int);
    const size_t lb_pay   = (size_t)NC * BD * sizeof(float);
    const size_t lb_bytes = 256 + lb_flags + 3 * lb_pay;

    bool bf16_path = false;
    size_t avail = ws_size;
    char* scan_ws = (char*)d_ws;
    if (ws_size >= bf16_bytes) {
        bf16_path = true;
        avail   -= bf16_bytes;
        scan_ws += bf16_bytes;
    }

    // Scan mode: 2 = lookback single-pass, 1 = 3-phase, 0 = sequential.
    int mode = 0, nc = 0;
    if (avail >= lb_bytes) mode = 2;
    else if (avail >= 3 * (size_t)128 * BD * sizeof(float)) { mode = 1; nc = 128; }
    else if (avail >= 3 * (size_t)32  * BD * sizeof(float)) { mode = 1; nc = 32; }

    // 1) Zero lookback control state first (stream-serialized before scan).
    if (mode == 2) {
        unsigned int* tick  = (unsigned int*)scan_ws;
        const int n4 = (int)((256 + lb_flags) / 16);
        zero_u32<<<dim3((n4 + 255) / 256), 256, 0, stream>>>(tick, n4);
    }

    // 2) Projection GEMMs.
    if (bf16_path) {
        short* xb  = (short*)d_ws;                       // [T*B, D] bf16
        short* Wkb = xb + TBD;                           // [D, D] bf16
        short* Wvb = Wkb + (size_t)D_DIM * D_DIM;
        cvt_f32_bf16<<<dim3((int)(TBD / 8 / 256)), 256, 0, stream>>>(x, xb, (int)(TBD / 8));
        cvt_f32_bf16<<<dim3(D_DIM * D_DIM / 8 / 256), 256, 0, stream>>>(Wk, Wkb, D_DIM * D_DIM / 8);
        cvt_f32_bf16<<<dim3(D_DIM * D_DIM / 8 / 256), 256, 0, stream>>>(Wv, Wvb, D_DIM * D_DIM / 8);
        gemm_kv_bf16<<<dim3(8, 256, 2), 256, 0, stream>>>(xb, Wkb, bk, Wvb, bv, kw, vw);
    } else {
        gemm_kv_f32src<<<dim3(8, 256, 2), 256, 0, stream>>>(x, Wk, bk, Wv, bv, kw, vw);
    }

    // 3) Scan.
    if (mode == 2) {
        unsigned int* tick  = (unsigned int*)scan_ws;
        unsigned int* flags = (unsigned int*)(scan_ws + 256);
        float* Apub = (float*)(scan_ws + 256 + lb_flags);
        float* Bpub = Apub + (size_t)NC * BD;
        float* Hpub = Bpub + (size_t)NC * BD;
        scan_lookback<<<dim3(NC * 64), 256, 0, stream>>>(
            kw, vw, h0, outp, hsec, tick, flags, Apub, Bpub, Hpub);
    } else if (mode == 1) {
        const int tc = T_DIM / nc;
        float* Aab   = (float*)scan_ws;
        float* Bab   = Aab + (size_t)nc * BD;
        float* Hinit = Bab + (size_t)nc * BD;
        scan_phase_a<<<dim3(BD / 256, nc), 256, 0, stream>>>(kw, vw, Aab, Bab, tc);
        scan_phase_b<<<dim3(BD / 256), 256, 0, stream>>>(h0, Aab, Bab, Hinit, hsec, nc);
        scan_phase_c<<<dim3(BD / 256, nc), 256, 0, stream>>>(kw, vw, Hinit, outp, hsec, tc);
    } else {
        scan_kernel<<<dim3(BD / 64), 64, 0, stream>>>(kw, vw, h0, outp, hsec);
    }
}

// Round 4
// 2311.258 us; speedup vs baseline: 1.5369x; 1.5369x over previous
//
#include <hip/hip_runtime.h>
#include <hip/hip_bf16.h>
#include <stdint.h>
#include <stddef.h>

// Problem constants (from reference): T=2048, B=16, D=1024. ALL I/O = float32.
#define T_DIM 2048
#define B_DIM 16
#define D_DIM 1024
#define BD    (B_DIM * D_DIM)          // 16384 state elements
#define TBD   ((size_t)T_DIM * BD)     // 33554432
#define NC    128                      // lookback chunks over T
#define TCH   (T_DIM / NC)             // 16 steps per chunk
#define NSL   (BD / 512)               // 32 slice-blocks per chunk (512 ch each)

using bf16 = __hip_bfloat16;
typedef __attribute__((ext_vector_type(8))) short short8;   // 8 x bf16 = 4 VGPRs
typedef __attribute__((ext_vector_type(4))) float f32x4;
typedef __attribute__((ext_vector_type(4))) unsigned int u32x4;

// f32 -> bf16 bits, round-to-nearest-even (finite inputs).
__device__ __forceinline__ unsigned f2bf(float f) {
    unsigned u = __float_as_uint(f);
    return (u + 0x7FFFu + ((u >> 16) & 1u)) >> 16;
}

// Agent-scope atomics for cross-XCD publish/consume (per-XCD L2 non-coherent).
__device__ __forceinline__ void st_rel_u32(unsigned int* p, unsigned int v) {
    __hip_atomic_store(p, v, __ATOMIC_RELEASE, __HIP_MEMORY_SCOPE_AGENT);
}
__device__ __forceinline__ unsigned int ld_acq_u32(const unsigned int* p) {
    return __hip_atomic_load(p, __ATOMIC_ACQUIRE, __HIP_MEMORY_SCOPE_AGENT);
}
union f2u64 { float2 f2; unsigned long long u; };
__device__ __forceinline__ void st_rlx_f2(float2* p, float2 v) {
    f2u64 t; t.f2 = v;
    __hip_atomic_store((unsigned long long*)p, t.u, __ATOMIC_RELAXED, __HIP_MEMORY_SCOPE_AGENT);
}
__device__ __forceinline__ float2 ld_rlx_f2(const float2* p) {
    f2u64 t;
    t.u = __hip_atomic_load((const unsigned long long*)p, __ATOMIC_RELAXED, __HIP_MEMORY_SCOPE_AGENT);
    return t.f2;
}

// ---------------------------------------------------------------------------
// f32 buffer -> bf16 buffer (for MFMA operands). 8 elems/thread.
// ---------------------------------------------------------------------------
__global__ __launch_bounds__(256) void cvt_f32_bf16(
    const float* __restrict__ src, short* __restrict__ dst, int n8)
{
    int i = blockIdx.x * 256 + threadIdx.x;
    if (i >= n8) return;
    const float* p = src + (size_t)i * 8;
    f32x4 a = *(const f32x4*)p;
    f32x4 b = *(const f32x4*)(p + 4);
    short8 r;
    r[0] = (short)f2bf(a[0]); r[1] = (short)f2bf(a[1]);
    r[2] = (short)f2bf(a[2]); r[3] = (short)f2bf(a[3]);
    r[4] = (short)f2bf(b[0]); r[5] = (short)f2bf(b[1]);
    r[6] = (short)f2bf(b[2]); r[7] = (short)f2bf(b[3]);
    *(short8*)(dst + (size_t)i * 8) = r;
}

// Zero a u32 region (ticket + flags) each launch; graph-capturable.
__global__ __launch_bounds__(256) void zero_u32(unsigned int* __restrict__ p, int n4)
{
    int i = blockIdx.x * 256 + threadIdx.x;
    if (i < n4) ((u32x4*)p)[i] = (u32x4){0u, 0u, 0u, 0u};
}

// ---------------------------------------------------------------------------
// async global->LDS, 16B per lane. LDS dest is wave-uniform base + lane*16.
// ---------------------------------------------------------------------------
typedef __attribute__((address_space(1))) void gvoid;
typedef __attribute__((address_space(3))) void lvoid;
__device__ __forceinline__ void gload_lds16(const short* g, short* l) {
    __builtin_amdgcn_global_load_lds((gvoid*)g, (lvoid*)l, 16, 0, 0);
}

// ---------------------------------------------------------------------------
// Fused K/V projection GEMM, m97 structure: 128x128 tile, BK=32, LDS
// double-buffered via global_load_lds width=16, ds_read_b128 fragments,
// one __syncthreads per K-step. XCD-chunked block swizzle (T1): FETCH_SIZE
// measured 531 -> 99 MB, dur 265 -> 227 us (R1).
//   pre[m][n] = sum_d x[m][d]*W[n][d]  (NT, both row-major K-fast)
//   z==0: k = sigmoid(pre+b_k); z==1: v = tanh(pre+b_v)
// ---------------------------------------------------------------------------
__global__ __launch_bounds__(256, 4) void gemm_kv_bf16(
    const short* __restrict__ xb,
    const short* __restrict__ Wkb, const float* __restrict__ bk,
    const short* __restrict__ Wvb, const float* __restrict__ bv,
    float* __restrict__ kout, float* __restrict__ vout)
{
    __shared__ short sA[2][128 * 32];   // 8KB per buffer
    __shared__ short sB[2][128 * 32];

    const int tid  = threadIdx.x;
    const int lane = tid & 63;
    const int wave = tid >> 6;
    const int wm   = wave & 1;
    const int wn   = wave >> 1;
    const int quad = lane >> 4;
    const int l15  = lane & 15;

    // XCD-chunked swizzle: nwg=4096, 8 XCDs, 512 tiles/XCD (bijective).
    const int lin = blockIdx.x + (blockIdx.y << 3) + (blockIdx.z << 11);
    const int swz = ((lin & 7) << 9) | (lin >> 3);
    const bool is_k = (swz >> 11) == 0;
    const int blkm = (swz >> 3) & 255;   // 0..255
    const int blkn = swz & 7;            // 0..7

    const short* W    = is_k ? Wkb : Wvb;
    const float* bias = is_k ? bk : bv;
    float*       outp = is_k ? kout : vout;

    const int m0 = blkm * 128;
    const int n0 = blkn * 128;

    const int srow = wave * 16 + (lane >> 2);        // 0..63 within half
    const int skof = (lane & 3) * 8;                 // shorts
    const short* ga = xb + (size_t)(m0 + srow) * D_DIM + skof;
    const short* gb = W  + (size_t)(n0 + srow) * D_DIM + skof;
    const int lofs = wave * 512;                     // wave*16 rows * 32 shorts

    auto STAGE = [&](int buf, int ks) {
        const size_t ko = (size_t)ks * 32;
        gload_lds16(ga + ko,                        &sA[buf][lofs]);
        gload_lds16(ga + ko + (size_t)64 * D_DIM,   &sA[buf][2048 + lofs]);
        gload_lds16(gb + ko,                        &sB[buf][lofs]);
        gload_lds16(gb + ko + (size_t)64 * D_DIM,   &sB[buf][2048 + lofs]);
    };

    f32x4 acc[4][4] = {};

    STAGE(0, 0);
    int cur = 0;
    for (int ks = 0; ks < D_DIM / 32; ++ks) {
        __syncthreads();
        if (ks + 1 < D_DIM / 32) STAGE(cur ^ 1, ks + 1);

        const short* lA = sA[cur];
        const short* lB = sB[cur];
        short8 a[4], b[4];
#pragma unroll
        for (int mt = 0; mt < 4; ++mt)
            a[mt] = *(const short8*)&lA[(wm * 64 + mt * 16 + l15) * 32 + quad * 8];
#pragma unroll
        for (int nt = 0; nt < 4; ++nt)
            b[nt] = *(const short8*)&lB[(wn * 64 + nt * 16 + l15) * 32 + quad * 8];
#pragma unroll
        for (int mt = 0; mt < 4; ++mt)
#pragma unroll
            for (int nt = 0; nt < 4; ++nt)
                acc[mt][nt] = __builtin_amdgcn_mfma_f32_16x16x32_bf16(
                    a[mt], b[nt], acc[mt][nt], 0, 0, 0);
        cur ^= 1;
    }

    const int gm0 = blkm * 128 + wm * 64 + quad * 4;
    const int gn  = blkn * 128 + wn * 64 + l15;
#pragma unroll
    for (int nt = 0; nt < 4; ++nt) {
        const int n = gn + nt * 16;
        const float bs = bias[n];
#pragma unroll
        for (int mt = 0; mt < 4; ++mt) {
            const int m = gm0 + mt * 16;
#pragma unroll
            for (int r = 0; r < 4; ++r) {
                float pre = acc[mt][nt][r] + bs;
                pre = fminf(20.f, fmaxf(-20.f, pre));
                float o;
                if (is_k) o = 1.f / (1.f + __expf(-pre));                // sigmoid
                else      o = 2.f / (1.f + __expf(-2.f * pre)) - 1.f;    // tanh
                outp[(size_t)(m + r) * D_DIM + n] = o;
            }
        }
    }
}

// ---------------------------------------------------------------------------
// Fallback GEMM when ws too small: load f32 operands, convert in-kernel.
// ---------------------------------------------------------------------------
__device__ __forceinline__ short8 load_cvt8(const float* p) {
    f32x4 a = *(const f32x4*)p;
    f32x4 b = *(const f32x4*)(p + 4);
    short8 r;
    r[0] = (short)f2bf(a[0]); r[1] = (short)f2bf(a[1]);
    r[2] = (short)f2bf(a[2]); r[3] = (short)f2bf(a[3]);
    r[4] = (short)f2bf(b[0]); r[5] = (short)f2bf(b[1]);
    r[6] = (short)f2bf(b[2]); r[7] = (short)f2bf(b[3]);
    return r;
}

__global__ __launch_bounds__(256) void gemm_kv_f32src(
    const float* __restrict__ x,
    const float* __restrict__ Wk, const float* __restrict__ bk,
    const float* __restrict__ Wv, const float* __restrict__ bv,
    float* __restrict__ kout, float* __restrict__ vout)
{
    const int tid  = threadIdx.x;
    const int lane = tid & 63;
    const int wave = tid >> 6;
    const int wm   = wave & 1;
    const int wn   = wave >> 1;
    const int quad = lane >> 4;
    const int l15  = lane & 15;

    const int blkn = blockIdx.x;
    const int blkm = blockIdx.y;
    const bool is_k = (blockIdx.z == 0);

    const float* W    = is_k ? Wk : Wv;
    const float* bias = is_k ? bk : bv;
    float*       outp = is_k ? kout : vout;

    const int m0 = blkm * 128 + wm * 64;
    const int n0 = blkn * 128 + wn * 64;

    const float* ap = x + (size_t)(m0 + l15) * D_DIM + quad * 8;
    const float* bp = W + (size_t)(n0 + l15) * D_DIM + quad * 8;

    f32x4 acc[4][4] = {};

    for (int ks = 0; ks < D_DIM / 32; ++ks) {
        short8 a[4], b[4];
#pragma unroll
        for (int mt = 0; mt < 4; ++mt)
            a[mt] = load_cvt8(ap + (size_t)mt * 16 * D_DIM + ks * 32);
#pragma unroll
        for (int nt = 0; nt < 4; ++nt)
            b[nt] = load_cvt8(bp + (size_t)nt * 16 * D_DIM + ks * 32);
#pragma unroll
        for (int mt = 0; mt < 4; ++mt)
#pragma unroll
            for (int nt = 0; nt < 4; ++nt)
                acc[mt][nt] = __builtin_amdgcn_mfma_f32_16x16x32_bf16(
                    a[mt], b[nt], acc[mt][nt], 0, 0, 0);
    }

    const int gm0 = blkm * 128 + wm * 64 + quad * 4;
    const int gn  = blkn * 128 + wn * 64 + l15;
#pragma unroll
    for (int nt = 0; nt < 4; ++nt) {
        const int n = gn + nt * 16;
        const float bs = bias[n];
#pragma unroll
        for (int mt = 0; mt < 4; ++mt) {
            const int m = gm0 + mt * 16;
#pragma unroll
            for (int r = 0; r < 4; ++r) {
                float pre = acc[mt][nt][r] + bs;
                pre = fminf(20.f, fmaxf(-20.f, pre));
                float o;
                if (is_k) o = 1.f / (1.f + __expf(-pre));
                else      o = 2.f / (1.f + __expf(-2.f * pre)) - 1.f;
                outp[(size_t)(m + r) * D_DIM + n] = o;
            }
        }
    }
}

// ---------------------------------------------------------------------------
// Single-pass decoupled-lookback scan of h_t = (1-k_t) h_{t-1} + k_t v_t.
// One block = (chunk c of TCH=16 steps, 512-channel slice; 2 ch/thread as
// float2). k/v stay in registers: one read, one write (minimal traffic).
//
// R3 lesson: per-channel flag spinning by all 64 lanes flooded the fabric
// (VALUBusy 1%, 15x regression). Now: ONE u32 flag per (chunk,slice) pair,
// polled by ONE thread with s_sleep backoff, broadcast via LDS+barrier.
// Publish protocol: payload relaxed-agent stores -> __threadfence() ->
// __syncthreads() -> single release flag store. Consumer: acquire flag poll
// by thread 0 -> __syncthreads() -> relaxed-agent payload loads. The
// inclusive prefix is published BEFORE the replay/store phase so the serial
// cross-chunk chain carries only {poll, 8B load, fma, fence}.
//
// Deadlock-free: blocks grab a ticket via atomicAdd at start (ticket order =
// start order); ticket tk -> chunk c = tk/NSL. A block waits only on chunks
// c' < c whose tickets are strictly smaller, i.e. blocks that already
// started; workgroups are non-preemptive, so predecessors complete.
//
// In-place aliasing (kw==outp, vw==hsec+BD): each block reads only its own
// chunk's (t,ch) slots and later writes exactly those slots from the same
// thread -> read-before-write within thread, disjoint across blocks.
// ---------------------------------------------------------------------------
__global__ __launch_bounds__(256) void scan_lookback(
    const float* kw, const float* vw, const float* __restrict__ h0,
    float* outp, float* hsec,
    unsigned int* __restrict__ ticket,
    unsigned int* __restrict__ aggf,   // [NC*NSL]
    unsigned int* __restrict__ incf,   // [NC*NSL]
    float2* __restrict__ ABp,          // [NC*BD]  (A,B) per channel
    float2* __restrict__ Hp2)          // [NC*BD/2] inclusive h, channel pairs
{
    __shared__ int s_ticket;
    __shared__ unsigned int s_flag;
    const int tid = threadIdx.x;
    if (tid == 0) s_ticket = (int)atomicAdd(ticket, 1u);
    __syncthreads();
    const int tk    = s_ticket;
    const int c     = tk / NSL;            // 0..NC-1 (early tickets -> low c)
    const int slice = tk % NSL;            // 0..NSL-1
    const int pair  = slice * 256 + tid;   // 0..BD/2-1 (channel pair index)
    const int ch0   = pair * 2;

    const int PB = BD / 2;                 // pairs per t-step
    const float2* kp2 = (const float2*)kw + (size_t)c * TCH * PB + pair;
    const float2* vp2 = (const float2*)vw + (size_t)c * TCH * PB + pair;

    float2 kk2[TCH], vv2[TCH];
#pragma unroll
    for (int j = 0; j < TCH; ++j) {
        kk2[j] = kp2[(size_t)j * PB];
        vv2[j] = vp2[(size_t)j * PB];
    }

    // Local chunk transform per channel: h_out = A*h_in + B.
    float A0 = 1.f, B0 = 0.f, A1 = 1.f, B1 = 0.f;
#pragma unroll
    for (int j = 0; j < TCH; ++j) {
        const float a0 = 1.f - kk2[j].x;
        B0 = a0 * B0 + kk2[j].x * vv2[j].x;  A0 *= a0;
        const float a1 = 1.f - kk2[j].y;
        B1 = a1 * B1 + kk2[j].y * vv2[j].y;  A1 *= a1;
    }

    float h0s, h1s;
    if (c == 0) {
        const float2 hh = ((const float2*)h0)[pair];
        h0s = hh.x; h1s = hh.y;
        ((float2*)hsec)[pair] = hh;                      // h[0] = h0
    } else {
        // Publish aggregate so successors can compose past us while we wait.
        st_rlx_f2(&ABp[(size_t)c * BD + ch0],     make_float2(A0, B0));
        st_rlx_f2(&ABp[(size_t)c * BD + ch0 + 1], make_float2(A1, B1));
        __threadfence();
        __syncthreads();
        if (tid == 0) st_rel_u32(&aggf[c * NSL + slice], 1u);

        // Lookback: h_start = aR * P_j + bR over j = c-1, c-2, ...
        float aR0 = 1.f, bR0 = 0.f, aR1 = 1.f, bR1 = 0.f;
        int j = c - 1;
        for (;;) {
            if (tid == 0) {
                unsigned int f;
                const int fi = j * NSL + slice;
                for (;;) {
                    if (ld_acq_u32(&incf[fi])) { f = 2u; break; }
                    if (ld_acq_u32(&aggf[fi])) { f = 1u; break; }
                    __builtin_amdgcn_s_sleep(16);
                }
                s_flag = f;
            }
            __syncthreads();
            const unsigned int f = s_flag;
            if (f == 2u) {                               // inclusive ready
                const float2 hh = ld_rlx_f2(&Hp2[(size_t)j * PB + pair]);
                h0s = aR0 * hh.x + bR0;
                h1s = aR1 * hh.y + bR1;
                break;
            }
            const float2 ab0 = ld_rlx_f2(&ABp[(size_t)j * BD + ch0]);
            const float2 ab1 = ld_rlx_f2(&ABp[(size_t)j * BD + ch0 + 1]);
            bR0 += aR0 * ab0.y;  aR0 *= ab0.x;
            bR1 += aR1 * ab1.y;  aR1 *= ab1.x;
            --j;                                          // chunk 0 always inc
            __syncthreads();                              // protect s_flag
        }
    }

    // Publish inclusive prefix FIRST (unblocks the chain), then replay.
    st_rlx_f2(&Hp2[(size_t)c * PB + pair],
              make_float2(A0 * h0s + B0, A1 * h1s + B1));
    __threadfence();
    __syncthreads();
    if (tid == 0) st_rel_u32(&incf[c * NSL + slice], 1u);

    float ha = h0s, hb = h1s;
    float2* op2 = (float2*)outp + (size_t)c * TCH * PB + pair;
    float2* hp2 = (float2*)hsec + ((size_t)c * TCH + 1) * PB + pair;
#pragma unroll
    for (int j = 0; j < TCH; ++j) {
        ha = (1.f - kk2[j].x) * ha + kk2[j].x * vv2[j].x;
        hb = (1.f - kk2[j].y) * hb + kk2[j].y * vv2[j].y;
        hp2[(size_t)j * PB] = make_float2(ha, hb);
        const float sa = 1.f / (1.f + __expf(-ha));
        const float sb = 1.f / (1.f + __expf(-hb));
        op2[(size_t)j * PB] = make_float2(ha * ha * sa, hb * hb * sb);
    }
}

// ---------------------------------------------------------------------------
// Fallback 3-phase chunked scan (kept for small-ws paths).
// ---------------------------------------------------------------------------
__global__ __launch_bounds__(256) void scan_phase_a(
    const float* kw, const float* vw,
    float* __restrict__ Aab, float* __restrict__ Bab, int tc)
{
    const int bd = blockIdx.x * 256 + threadIdx.x;
    const int c  = blockIdx.y;
    const float* kp = kw + (size_t)c * tc * BD + bd;
    const float* vp = vw + (size_t)c * tc * BD + bd;

    float A = 1.f, Bv = 0.f;
    for (int t0 = 0; t0 < tc; t0 += 16) {
        float kk[16], vv[16];
#pragma unroll
        for (int j = 0; j < 16; ++j) {
            kk[j] = kp[(size_t)(t0 + j) * BD];
            vv[j] = vp[(size_t)(t0 + j) * BD];
        }
#pragma unroll
        for (int j = 0; j < 16; ++j) {
            const float a = 1.f - kk[j];
            A  = A * a;
            Bv = a * Bv + kk[j] * vv[j];
        }
    }
    Aab[(size_t)c * BD + bd] = A;
    Bab[(size_t)c * BD + bd] = Bv;
}

__global__ __launch_bounds__(256) void scan_phase_b(
    const float* __restrict__ h0,
    const float* __restrict__ Aab, const float* __restrict__ Bab,
    float* __restrict__ Hinit, float* hsec, int nc)
{
    const int bd = blockIdx.x * 256 + threadIdx.x;
    float h = h0[bd];
    hsec[bd] = h;
    for (int c0 = 0; c0 < nc; c0 += 16) {
        float aa[16], bb[16];
#pragma unroll
        for (int j = 0; j < 16; ++j) {
            aa[j] = Aab[(size_t)(c0 + j) * BD + bd];
            bb[j] = Bab[(size_t)(c0 + j) * BD + bd];
        }
#pragma unroll
        for (int j = 0; j < 16; ++j) {
            Hinit[(size_t)(c0 + j) * BD + bd] = h;
            h = aa[j] * h + bb[j];
        }
    }
}

__global__ __launch_bounds__(256) void scan_phase_c(
    const float* kw, const float* vw, const float* __restrict__ Hinit,
    float* outp, float* hsec, int tc)
{
    const int bd = blockIdx.x * 256 + threadIdx.x;
    const int c  = blockIdx.y;
    float h = Hinit[(size_t)c * BD + bd];

    const size_t base = (size_t)c * tc * BD + bd;
    const float* kp = kw + base;
    const float* vp = vw + base;
    float* op = outp + base;
    float* hp = hsec + base + BD;

    float kk[16], vv[16];
#pragma unroll
    for (int j = 0; j < 16; ++j) {
        kk[j] = kp[(size_t)j * BD];
        vv[j] = vp[(size_t)j * BD];
    }
    for (int t0 = 0; t0 < tc; t0 += 16) {
        float kn[16], vn[16];
        if (t0 + 16 < tc) {
#pragma unroll
            for (int j = 0; j < 16; ++j) {
                kn[j] = kp[(size_t)(t0 + 16 + j) * BD];
                vn[j] = vp[(size_t)(t0 + 16 + j) * BD];
            }
        }
#pragma unroll
        for (int j = 0; j < 16; ++j) {
            h = (1.f - kk[j]) * h + kk[j] * vv[j];
            hp[(size_t)(t0 + j) * BD] = h;
            const float sig = 1.f / (1.f + __expf(-h));
            op[(size_t)(t0 + j) * BD] = h * h * sig;
        }
        if (t0 + 16 < tc) {
#pragma unroll
            for (int j = 0; j < 16; ++j) { kk[j] = kn[j]; vv[j] = vn[j]; }
        }
    }
}

// ---------------------------------------------------------------------------
// Fallback sequential scan (ws too small for any chunk buffers).
// ---------------------------------------------------------------------------
__global__ __launch_bounds__(64) void scan_kernel(
    const float* kw, const float* vw, const float* h0,
    float* outp, float* hsec)
{
    const int c = blockIdx.x * 64 + threadIdx.x;
    float h = h0[c];
    hsec[c] = h;

    const float* kp = kw + c;
    const float* vp = vw + c;
    float* op = outp + c;
    float* hp = hsec + BD + c;

    for (int t = 0; t < T_DIM; t += 8) {
        float kk[8], vv[8];
#pragma unroll
        for (int j = 0; j < 8; ++j) {
            kk[j] = kp[(size_t)(t + j) * BD];
            vv[j] = vp[(size_t)(t + j) * BD];
        }
#pragma unroll
        for (int j = 0; j < 8; ++j) {
            h = (1.f - kk[j]) * h + kk[j] * vv[j];
            hp[(size_t)(t + j) * BD] = h;
            const float sig = 1.f / (1.f + __expf(-h));
            op[(size_t)(t + j) * BD] = h * h * sig;
        }
    }
}

// ---------------------------------------------------------------------------
extern "C" void kernel_launch(void* const* d_in, const int* in_sizes, int n_in,
                              void* d_out, int out_size, void* d_ws, size_t ws_size,
                              hipStream_t stream)
{
    const float* x  = (const float*)d_in[0];   // [T,B,D]
    const float* h0 = (const float*)d_in[1];   // [B,D]
    const float* Wk = (const float*)d_in[2];   // [D,D]
    const float* bk = (const float*)d_in[3];   // [D]
    const float* Wv = (const float*)d_in[4];   // [D,D]
    const float* bv = (const float*)d_in[5];   // [D]

    float* outp = (float*)d_out;               // output section [T,B,D]
    float* hsec = outp + TBD;                  // h section [T+1,B,D]

    // k -> output section, v -> h[1:] section: element-exact in-place (safe,
    // see scan comments). No workspace needed for k/v themselves.
    float* kw = outp;
    float* vw = hsec + BD;

    const size_t bf16_bytes = (TBD + 2 * (size_t)D_DIM * D_DIM) * sizeof(short);
    // Lookback region: [ticket pad 256][aggf][incf][ABp float2/ch][Hp2].
    const size_t lb_flags = (size_t)NC * NSL * sizeof(unsigned int);   // 16KB
    const size_t lb_ctrl  = 256 + 2 * lb_flags;                        // 33024
    const size_t lb_ab    = (size_t)NC * BD * sizeof(float2);          // 16MB
    const size_t lb_h     = (size_t)NC * (BD / 2) * sizeof(float2);    // 8MB
    const size_t lb_bytes = lb_ctrl + lb_ab + lb_h;

    bool bf16_path = false;
    size_t avail = ws_size;
    char* scan_ws = (char*)d_ws;
    if (ws_size >= bf16_bytes) {
        bf16_path = true;
        avail   -= bf16_bytes;
        scan_ws += bf16_bytes;
    }

    // Scan mode: 2 = lookback single-pass, 1 = 3-phase, 0 = sequential.
    int mode = 0, nc = 0;
    if (avail >= lb_bytes) mode = 2;
    else if (avail >= 3 * (size_t)128 * BD * sizeof(float)) { mode = 1; nc = 128; }
    else if (avail >= 3 * (size_t)32  * BD * sizeof(float)) { mode = 1; nc = 32; }

    // 1) Zero lookback control state first (stream-serialized before scan).
    if (mode == 2) {
        unsigned int* ctrl = (unsigned int*)scan_ws;
        const int n4 = (int)(lb_ctrl / 16);
        zero_u32<<<dim3((n4 + 255) / 256), 256, 0, stream>>>(ctrl, n4);
    }

    // 2) Projection GEMMs.
    if (bf16_path) {
        short* xb  = (short*)d_ws;                       // [T*B, D] bf16
        short* Wkb = xb + TBD;                           // [D, D] bf16
        short* Wvb = Wkb + (size_t)D_DIM * D_DIM;
        cvt_f32_bf16<<<dim3((int)(TBD / 8 / 256)), 256, 0, stream>>>(x, xb, (int)(TBD / 8));
        cvt_f32_bf16<<<dim3(D_DIM * D_DIM / 8 / 256), 256, 0, stream>>>(Wk, Wkb, D_DIM * D_DIM / 8);
        cvt_f32_bf16<<<dim3(D_DIM * D_DIM / 8 / 256), 256, 0, stream>>>(Wv, Wvb, D_DIM * D_DIM / 8);
        gemm_kv_bf16<<<dim3(8, 256, 2), 256, 0, stream>>>(xb, Wkb, bk, Wvb, bv, kw, vw);
    } else {
        gemm_kv_f32src<<<dim3(8, 256, 2), 256, 0, stream>>>(x, Wk, bk, Wv, bv, kw, vw);
    }

    // 3) Scan.
    if (mode == 2) {
        unsigned int* tick = (unsigned int*)scan_ws;
        unsigned int* aggf = (unsigned int*)(scan_ws + 256);
        unsigned int* incf = aggf + (size_t)NC * NSL;
        float2* ABp = (float2*)(scan_ws + lb_ctrl);
        float2* Hp2 = (float2*)(scan_ws + lb_ctrl + lb_ab);
        scan_lookback<<<dim3(NC * NSL), 256, 0, stream>>>(
            kw, vw, h0, outp, hsec, tick, aggf, incf, ABp, Hp2);
    } else if (mode == 1) {
        const int tc = T_DIM / nc;
        float* Aab   = (float*)scan_ws;
        float* Bab   = Aab + (size_t)nc * BD;
        float* Hinit = Bab + (size_t)nc * BD;
        scan_phase_a<<<dim3(BD / 256, nc), 256, 0, stream>>>(kw, vw, Aab, Bab, tc);
        scan_phase_b<<<dim3(BD / 256), 256, 0, stream>>>(h0, Aab, Bab, Hinit, hsec, nc);
        scan_phase_c<<<dim3(BD / 256, nc), 256, 0, stream>>>(kw, vw, Hinit, outp, hsec, tc);
    } else {
        scan_kernel<<<dim3(BD / 64), 64, 0, stream>>>(kw, vw, h0, outp, hsec);
    }
}

// Round 5
// 707.802 us; speedup vs baseline: 5.0188x; 3.2654x over previous
//
#include <hip/hip_runtime.h>
#include <hip/hip_bf16.h>
#include <stdint.h>
#include <stddef.h>

// Problem constants (from reference): T=2048, B=16, D=1024. ALL I/O = float32.
#define T_DIM 2048
#define B_DIM 16
#define D_DIM 1024
#define BD    (B_DIM * D_DIM)          // 16384 state elements
#define TBD   ((size_t)T_DIM * BD)     // 33554432
#define NG    256                      // t-groups (one per gemm m-tile)
#define TG    8                        // steps per t-group

using bf16 = __hip_bfloat16;
typedef __attribute__((ext_vector_type(8))) short short8;   // 8 x bf16 = 4 VGPRs
typedef __attribute__((ext_vector_type(4))) float f32x4;

// f32 -> bf16 bits, round-to-nearest-even (finite inputs).
__device__ __forceinline__ unsigned f2bf(float f) {
    unsigned u = __float_as_uint(f);
    return (u + 0x7FFFu + ((u >> 16) & 1u)) >> 16;
}

// ---------------------------------------------------------------------------
// f32 buffer -> bf16 buffer (for MFMA operands). 8 elems/thread.
// ---------------------------------------------------------------------------
__global__ __launch_bounds__(256) void cvt_f32_bf16(
    const float* __restrict__ src, short* __restrict__ dst, int n8)
{
    int i = blockIdx.x * 256 + threadIdx.x;
    if (i >= n8) return;
    const float* p = src + (size_t)i * 8;
    f32x4 a = *(const f32x4*)p;
    f32x4 b = *(const f32x4*)(p + 4);
    short8 r;
    r[0] = (short)f2bf(a[0]); r[1] = (short)f2bf(a[1]);
    r[2] = (short)f2bf(a[2]); r[3] = (short)f2bf(a[3]);
    r[4] = (short)f2bf(b[0]); r[5] = (short)f2bf(b[1]);
    r[6] = (short)f2bf(b[2]); r[7] = (short)f2bf(b[3]);
    *(short8*)(dst + (size_t)i * 8) = r;
}

// ---------------------------------------------------------------------------
// async global->LDS, 16B per lane. LDS dest is wave-uniform base + lane*16.
// ---------------------------------------------------------------------------
typedef __attribute__((address_space(1))) void gvoid;
typedef __attribute__((address_space(3))) void lvoid;
__device__ __forceinline__ void gload_lds16(const short* g, short* l) {
    __builtin_amdgcn_global_load_lds((gvoid*)g, (lvoid*)l, 16, 0, 0);
}

__device__ __forceinline__ float sigm(float x) {
    x = fminf(20.f, fmaxf(-20.f, x));
    return 1.f / (1.f + __expf(-x));
}
__device__ __forceinline__ float tanh_(float x) {
    x = fminf(20.f, fmaxf(-20.f, x));
    return 2.f / (1.f + __expf(-2.f * x)) - 1.f;
}

// ---------------------------------------------------------------------------
// Z-MERGED fused K/V projection GEMM + phase-A aggregation epilogue.
// One block computes BOTH k and v for a 128x128 tile (shares the x A-tile:
// 32 MFMA per 24KB staged vs 16 per 16KB in the split version).
// m97 staging structure (global_load_lds w=16, double-buffered, 1 barrier/K).
// Rows m = t*16+b: a thread's accumulator rows have b = quad*4+r and
// t = blkm*8 + wm*4 + mt (from the verified C/D map col=l&15,row=quad*4+r).
// Epilogue: per (channel, thread) compose the 4-step affine transform of
//   h <- (1-k)h + k v ; LDS-combine wm=0 (t 0..3) with wm=1 (t 4..7) into an
// 8-step aggregate (A8,B8) per channel, stored to agg[blkm*BD + b*D + d].
// This makes the scan's phase A free (no 268MB re-read of k/v).
// ---------------------------------------------------------------------------
__global__ __launch_bounds__(256, 2) void gemm_kv_fused(
    const short* __restrict__ xb,
    const short* __restrict__ Wkb, const float* __restrict__ bk,
    const short* __restrict__ Wvb, const float* __restrict__ bv,
    float* __restrict__ kout, float* __restrict__ vout,
    float2* __restrict__ agg)
{
    __shared__ short sA[2][128 * 32];    // 16KB (also reused as 16KB float2 for combine)
    __shared__ short sBk[2][128 * 32];   // 16KB
    __shared__ short sBv[2][128 * 32];   // 16KB

    const int tid  = threadIdx.x;
    const int lane = tid & 63;
    const int wave = tid >> 6;
    const int wm   = wave & 1;
    const int wn   = wave >> 1;
    const int quad = lane >> 4;
    const int l15  = lane & 15;

    // XCD-chunked swizzle: 2048 blocks, 256/XCD; per XCD a contiguous blkm
    // range with ALL blkn (x-panel L2 reuse; R1: FETCH 531->99MB).
    const int lin = blockIdx.x + (blockIdx.y << 3);
    const int swz = ((lin & 7) << 8) | (lin >> 3);
    const int blkm = swz >> 3;           // 0..255
    const int blkn = swz & 7;            // 0..7

    const int m0 = blkm * 128;
    const int n0 = blkn * 128;

    const int srow = wave * 16 + (lane >> 2);        // 0..63 within half
    const int skof = (lane & 3) * 8;                 // shorts
    const short* ga = xb  + (size_t)(m0 + srow) * D_DIM + skof;
    const short* gk = Wkb + (size_t)(n0 + srow) * D_DIM + skof;
    const short* gv = Wvb + (size_t)(n0 + srow) * D_DIM + skof;
    const int lofs = wave * 512;                     // wave*16 rows * 32 shorts

    auto STAGE = [&](int buf, int ks) {
        const size_t ko = (size_t)ks * 32;
        gload_lds16(ga + ko,                        &sA[buf][lofs]);
        gload_lds16(ga + ko + (size_t)64 * D_DIM,   &sA[buf][2048 + lofs]);
        gload_lds16(gk + ko,                        &sBk[buf][lofs]);
        gload_lds16(gk + ko + (size_t)64 * D_DIM,   &sBk[buf][2048 + lofs]);
        gload_lds16(gv + ko,                        &sBv[buf][lofs]);
        gload_lds16(gv + ko + (size_t)64 * D_DIM,   &sBv[buf][2048 + lofs]);
    };

    f32x4 ack[4][4] = {};
    f32x4 acv[4][4] = {};

    STAGE(0, 0);
    int cur = 0;
    for (int ks = 0; ks < D_DIM / 32; ++ks) {
        __syncthreads();
        if (ks + 1 < D_DIM / 32) STAGE(cur ^ 1, ks + 1);

        const short* lA = sA[cur];
        const short* lK = sBk[cur];
        const short* lV = sBv[cur];
        short8 a[4], bkf[4], bvf[4];
#pragma unroll
        for (int mt = 0; mt < 4; ++mt)
            a[mt] = *(const short8*)&lA[(wm * 64 + mt * 16 + l15) * 32 + quad * 8];
#pragma unroll
        for (int nt = 0; nt < 4; ++nt) {
            bkf[nt] = *(const short8*)&lK[(wn * 64 + nt * 16 + l15) * 32 + quad * 8];
            bvf[nt] = *(const short8*)&lV[(wn * 64 + nt * 16 + l15) * 32 + quad * 8];
        }
#pragma unroll
        for (int mt = 0; mt < 4; ++mt)
#pragma unroll
            for (int nt = 0; nt < 4; ++nt) {
                ack[mt][nt] = __builtin_amdgcn_mfma_f32_16x16x32_bf16(
                    a[mt], bkf[nt], ack[mt][nt], 0, 0, 0);
                acv[mt][nt] = __builtin_amdgcn_mfma_f32_16x16x32_bf16(
                    a[mt], bvf[nt], acv[mt][nt], 0, 0, 0);
            }
        cur ^= 1;
    }

    // Epilogue: activations + element stores + 4-step affine partials.
    const int gm0 = blkm * 128 + wm * 64 + quad * 4;
    const int gn  = n0 + wn * 64 + l15;
    float2 part[4][4];                               // [nt][r] = (A4,B4)
#pragma unroll
    for (int nt = 0; nt < 4; ++nt) {
        const int n = gn + nt * 16;
        const float bks = bk[n];
        const float bvs = bv[n];
#pragma unroll
        for (int r = 0; r < 4; ++r) {
            float A = 1.f, Bv = 0.f;
#pragma unroll
            for (int mt = 0; mt < 4; ++mt) {         // ascending t
                const int m = gm0 + mt * 16 + r;
                const float ke = sigm(ack[mt][nt][r] + bks);
                const float ve = tanh_(acv[mt][nt][r] + bvs);
                kout[(size_t)m * D_DIM + n] = ke;
                vout[(size_t)m * D_DIM + n] = ve;
                const float a1 = 1.f - ke;
                Bv = a1 * Bv + ke * ve;
                A *= a1;
            }
            part[nt][r] = make_float2(A, Bv);
        }
    }

    // Combine wm halves: h_out = T_hi(T_lo(h)) -> A8 = Ah*Al, B8 = Ah*Bl+Bh.
    __syncthreads();                                  // done reading K-loop LDS
    float2* lp = (float2*)sA;                         // [16][128] = 16KB
    if (wm == 1) {
#pragma unroll
        for (int nt = 0; nt < 4; ++nt)
#pragma unroll
            for (int r = 0; r < 4; ++r)
                lp[(quad * 4 + r) * 128 + wn * 64 + nt * 16 + l15] = part[nt][r];
    }
    __syncthreads();
    if (wm == 0) {
#pragma unroll
        for (int nt = 0; nt < 4; ++nt)
#pragma unroll
            for (int r = 0; r < 4; ++r) {
                const int b = quad * 4 + r;
                const int d = n0 + wn * 64 + nt * 16 + l15;
                const float2 hi = lp[b * 128 + wn * 64 + nt * 16 + l15];
                const float A8 = hi.x * part[nt][r].x;
                const float B8 = hi.x * part[nt][r].y + hi.y;
                agg[(size_t)blkm * BD + b * D_DIM + d] = make_float2(A8, B8);
            }
    }
}

// ---------------------------------------------------------------------------
// Fallback split GEMM (R1/R2 version) for small-ws paths.
// ---------------------------------------------------------------------------
__global__ __launch_bounds__(256, 4) void gemm_kv_bf16(
    const short* __restrict__ xb,
    const short* __restrict__ Wkb, const float* __restrict__ bk,
    const short* __restrict__ Wvb, const float* __restrict__ bv,
    float* __restrict__ kout, float* __restrict__ vout)
{
    __shared__ short sA[2][128 * 32];
    __shared__ short sB[2][128 * 32];

    const int tid  = threadIdx.x;
    const int lane = tid & 63;
    const int wave = tid >> 6;
    const int wm   = wave & 1;
    const int wn   = wave >> 1;
    const int quad = lane >> 4;
    const int l15  = lane & 15;

    const int lin = blockIdx.x + (blockIdx.y << 3) + (blockIdx.z << 11);
    const int swz = ((lin & 7) << 9) | (lin >> 3);
    const bool is_k = (swz >> 11) == 0;
    const int blkm = (swz >> 3) & 255;
    const int blkn = swz & 7;

    const short* W    = is_k ? Wkb : Wvb;
    const float* bias = is_k ? bk : bv;
    float*       outp = is_k ? kout : vout;

    const int m0 = blkm * 128;
    const int n0 = blkn * 128;

    const int srow = wave * 16 + (lane >> 2);
    const int skof = (lane & 3) * 8;
    const short* ga = xb + (size_t)(m0 + srow) * D_DIM + skof;
    const short* gb = W  + (size_t)(n0 + srow) * D_DIM + skof;
    const int lofs = wave * 512;

    auto STAGE = [&](int buf, int ks) {
        const size_t ko = (size_t)ks * 32;
        gload_lds16(ga + ko,                      &sA[buf][lofs]);
        gload_lds16(ga + ko + (size_t)64 * D_DIM, &sA[buf][2048 + lofs]);
        gload_lds16(gb + ko,                      &sB[buf][lofs]);
        gload_lds16(gb + ko + (size_t)64 * D_DIM, &sB[buf][2048 + lofs]);
    };

    f32x4 acc[4][4] = {};

    STAGE(0, 0);
    int cur = 0;
    for (int ks = 0; ks < D_DIM / 32; ++ks) {
        __syncthreads();
        if (ks + 1 < D_DIM / 32) STAGE(cur ^ 1, ks + 1);

        const short* lA = sA[cur];
        const short* lB = sB[cur];
        short8 a[4], b[4];
#pragma unroll
        for (int mt = 0; mt < 4; ++mt)
            a[mt] = *(const short8*)&lA[(wm * 64 + mt * 16 + l15) * 32 + quad * 8];
#pragma unroll
        for (int nt = 0; nt < 4; ++nt)
            b[nt] = *(const short8*)&lB[(wn * 64 + nt * 16 + l15) * 32 + quad * 8];
#pragma unroll
        for (int mt = 0; mt < 4; ++mt)
#pragma unroll
            for (int nt = 0; nt < 4; ++nt)
                acc[mt][nt] = __builtin_amdgcn_mfma_f32_16x16x32_bf16(
                    a[mt], b[nt], acc[mt][nt], 0, 0, 0);
        cur ^= 1;
    }

    const int gm0 = blkm * 128 + wm * 64 + quad * 4;
    const int gn  = blkn * 128 + wn * 64 + l15;
#pragma unroll
    for (int nt = 0; nt < 4; ++nt) {
        const int n = gn + nt * 16;
        const float bs = bias[n];
#pragma unroll
        for (int mt = 0; mt < 4; ++mt) {
            const int m = gm0 + mt * 16;
#pragma unroll
            for (int r = 0; r < 4; ++r) {
                const float pre = acc[mt][nt][r] + bs;
                outp[(size_t)(m + r) * D_DIM + n] = is_k ? sigm(pre) : tanh_(pre);
            }
        }
    }
}

// ---------------------------------------------------------------------------
// Fallback GEMM when ws too small for bf16 staging.
// ---------------------------------------------------------------------------
__device__ __forceinline__ short8 load_cvt8(const float* p) {
    f32x4 a = *(const f32x4*)p;
    f32x4 b = *(const f32x4*)(p + 4);
    short8 r;
    r[0] = (short)f2bf(a[0]); r[1] = (short)f2bf(a[1]);
    r[2] = (short)f2bf(a[2]); r[3] = (short)f2bf(a[3]);
    r[4] = (short)f2bf(b[0]); r[5] = (short)f2bf(b[1]);
    r[6] = (short)f2bf(b[2]); r[7] = (short)f2bf(b[3]);
    return r;
}

__global__ __launch_bounds__(256) void gemm_kv_f32src(
    const float* __restrict__ x,
    const float* __restrict__ Wk, const float* __restrict__ bk,
    const float* __restrict__ Wv, const float* __restrict__ bv,
    float* __restrict__ kout, float* __restrict__ vout)
{
    const int tid  = threadIdx.x;
    const int lane = tid & 63;
    const int wave = tid >> 6;
    const int wm   = wave & 1;
    const int wn   = wave >> 1;
    const int quad = lane >> 4;
    const int l15  = lane & 15;

    const int blkn = blockIdx.x;
    const int blkm = blockIdx.y;
    const bool is_k = (blockIdx.z == 0);

    const float* W    = is_k ? Wk : Wv;
    const float* bias = is_k ? bk : bv;
    float*       outp = is_k ? kout : vout;

    const int m0 = blkm * 128 + wm * 64;
    const int n0 = blkn * 128 + wn * 64;

    const float* ap = x + (size_t)(m0 + l15) * D_DIM + quad * 8;
    const float* bp = W + (size_t)(n0 + l15) * D_DIM + quad * 8;

    f32x4 acc[4][4] = {};

    for (int ks = 0; ks < D_DIM / 32; ++ks) {
        short8 a[4], b[4];
#pragma unroll
        for (int mt = 0; mt < 4; ++mt)
            a[mt] = load_cvt8(ap + (size_t)mt * 16 * D_DIM + ks * 32);
#pragma unroll
        for (int nt = 0; nt < 4; ++nt)
            b[nt] = load_cvt8(bp + (size_t)nt * 16 * D_DIM + ks * 32);
#pragma unroll
        for (int mt = 0; mt < 4; ++mt)
#pragma unroll
            for (int nt = 0; nt < 4; ++nt)
                acc[mt][nt] = __builtin_amdgcn_mfma_f32_16x16x32_bf16(
                    a[mt], b[nt], acc[mt][nt], 0, 0, 0);
    }

    const int gm0 = blkm * 128 + wm * 64 + quad * 4;
    const int gn  = blkn * 128 + wn * 64 + l15;
#pragma unroll
    for (int nt = 0; nt < 4; ++nt) {
        const int n = gn + nt * 16;
        const float bs = bias[n];
#pragma unroll
        for (int mt = 0; mt < 4; ++mt) {
            const int m = gm0 + mt * 16;
#pragma unroll
            for (int r = 0; r < 4; ++r) {
                const float pre = acc[mt][nt][r] + bs;
                outp[(size_t)(m + r) * D_DIM + n] = is_k ? sigm(pre) : tanh_(pre);
            }
        }
    }
}

// ---------------------------------------------------------------------------
// Phase B: compose the NG=256 8-step aggregates per channel (serial over tg,
// batched 16-deep loads). Overwrites agg[tg].x with h_start(tg) in place
// (read-before-write within the same thread), so phase C needs no extra
// buffer. Also writes h[0] = h0.
// ---------------------------------------------------------------------------
__global__ __launch_bounds__(256) void scan_hinit(
    const float* __restrict__ h0, float2* agg, float* hsec)
{
    const int ch = blockIdx.x * 256 + threadIdx.x;   // 0..BD-1
    float h = h0[ch];
    hsec[ch] = h;
    for (int g0 = 0; g0 < NG; g0 += 16) {
        float2 ag[16];
#pragma unroll
        for (int j = 0; j < 16; ++j)
            ag[j] = agg[(size_t)(g0 + j) * BD + ch];
#pragma unroll
        for (int j = 0; j < 16; ++j) {
            agg[(size_t)(g0 + j) * BD + ch].x = h;   // h_start for this tg
            h = ag[j].x * h + ag[j].y;
        }
    }
}

// ---------------------------------------------------------------------------
// Phase C: per (tgroup, channel) replay 8 steps with known h_start; write h
// and out. kw aliases outp, vw aliases hsec+BD: each thread reads its own
// (t,ch) slots strictly before overwriting them; blocks are disjoint.
// ---------------------------------------------------------------------------
__global__ __launch_bounds__(256) void scan_apply(
    const float* kw, const float* vw, const float2* __restrict__ agg,
    float* outp, float* hsec)
{
    const int ch = blockIdx.x * 256 + threadIdx.x;   // 0..BD-1
    const int tg = blockIdx.y;                       // 0..NG-1
    float h = agg[(size_t)tg * BD + ch].x;

    const size_t base = (size_t)tg * TG * BD + ch;
    const float* kp = kw + base;
    const float* vp = vw + base;
    float* op = outp + base;
    float* hp = hsec + base + BD;

    float kk[TG], vv[TG];
#pragma unroll
    for (int j = 0; j < TG; ++j) {
        kk[j] = kp[(size_t)j * BD];
        vv[j] = vp[(size_t)j * BD];
    }
#pragma unroll
    for (int j = 0; j < TG; ++j) {
        h = (1.f - kk[j]) * h + kk[j] * vv[j];
        hp[(size_t)j * BD] = h;
        const float sig = 1.f / (1.f + __expf(-h));
        op[(size_t)j * BD] = h * h * sig;
    }
}

// ---------------------------------------------------------------------------
// Fallback 3-phase chunked scan (small-ws paths).
// ---------------------------------------------------------------------------
__global__ __launch_bounds__(256) void scan_phase_a(
    const float* kw, const float* vw,
    float* __restrict__ Aab, float* __restrict__ Bab, int tc)
{
    const int bd = blockIdx.x * 256 + threadIdx.x;
    const int c  = blockIdx.y;
    const float* kp = kw + (size_t)c * tc * BD + bd;
    const float* vp = vw + (size_t)c * tc * BD + bd;

    float A = 1.f, Bv = 0.f;
    for (int t0 = 0; t0 < tc; t0 += 16) {
        float kk[16], vv[16];
#pragma unroll
        for (int j = 0; j < 16; ++j) {
            kk[j] = kp[(size_t)(t0 + j) * BD];
            vv[j] = vp[(size_t)(t0 + j) * BD];
        }
#pragma unroll
        for (int j = 0; j < 16; ++j) {
            const float a = 1.f - kk[j];
            A  = A * a;
            Bv = a * Bv + kk[j] * vv[j];
        }
    }
    Aab[(size_t)c * BD + bd] = A;
    Bab[(size_t)c * BD + bd] = Bv;
}

__global__ __launch_bounds__(256) void scan_phase_b(
    const float* __restrict__ h0,
    const float* __restrict__ Aab, const float* __restrict__ Bab,
    float* __restrict__ Hinit, float* hsec, int nc)
{
    const int bd = blockIdx.x * 256 + threadIdx.x;
    float h = h0[bd];
    hsec[bd] = h;
    for (int c0 = 0; c0 < nc; c0 += 16) {
        float aa[16], bb[16];
#pragma unroll
        for (int j = 0; j < 16; ++j) {
            aa[j] = Aab[(size_t)(c0 + j) * BD + bd];
            bb[j] = Bab[(size_t)(c0 + j) * BD + bd];
        }
#pragma unroll
        for (int j = 0; j < 16; ++j) {
            Hinit[(size_t)(c0 + j) * BD + bd] = h;
            h = aa[j] * h + bb[j];
        }
    }
}

__global__ __launch_bounds__(256) void scan_phase_c(
    const float* kw, const float* vw, const float* __restrict__ Hinit,
    float* outp, float* hsec, int tc)
{
    const int bd = blockIdx.x * 256 + threadIdx.x;
    const int c  = blockIdx.y;
    float h = Hinit[(size_t)c * BD + bd];

    const size_t base = (size_t)c * tc * BD + bd;
    const float* kp = kw + base;
    const float* vp = vw + base;
    float* op = outp + base;
    float* hp = hsec + base + BD;

    for (int t0 = 0; t0 < tc; t0 += 16) {
        float kk[16], vv[16];
#pragma unroll
        for (int j = 0; j < 16; ++j) {
            kk[j] = kp[(size_t)(t0 + j) * BD];
            vv[j] = vp[(size_t)(t0 + j) * BD];
        }
#pragma unroll
        for (int j = 0; j < 16; ++j) {
            h = (1.f - kk[j]) * h + kk[j] * vv[j];
            hp[(size_t)(t0 + j) * BD] = h;
            const float sig = 1.f / (1.f + __expf(-h));
            op[(size_t)(t0 + j) * BD] = h * h * sig;
        }
    }
}

// ---------------------------------------------------------------------------
// Fallback sequential scan (ws too small for any chunk buffers).
// ---------------------------------------------------------------------------
__global__ __launch_bounds__(64) void scan_kernel(
    const float* kw, const float* vw, const float* h0,
    float* outp, float* hsec)
{
    const int c = blockIdx.x * 64 + threadIdx.x;
    float h = h0[c];
    hsec[c] = h;

    const float* kp = kw + c;
    const float* vp = vw + c;
    float* op = outp + c;
    float* hp = hsec + BD + c;

    for (int t = 0; t < T_DIM; t += 8) {
        float kk[8], vv[8];
#pragma unroll
        for (int j = 0; j < 8; ++j) {
            kk[j] = kp[(size_t)(t + j) * BD];
            vv[j] = vp[(size_t)(t + j) * BD];
        }
#pragma unroll
        for (int j = 0; j < 8; ++j) {
            h = (1.f - kk[j]) * h + kk[j] * vv[j];
            hp[(size_t)(t + j) * BD] = h;
            const float sig = 1.f / (1.f + __expf(-h));
            op[(size_t)(t + j) * BD] = h * h * sig;
        }
    }
}

// ---------------------------------------------------------------------------
extern "C" void kernel_launch(void* const* d_in, const int* in_sizes, int n_in,
                              void* d_out, int out_size, void* d_ws, size_t ws_size,
                              hipStream_t stream)
{
    const float* x  = (const float*)d_in[0];   // [T,B,D]
    const float* h0 = (const float*)d_in[1];   // [B,D]
    const float* Wk = (const float*)d_in[2];   // [D,D]
    const float* bk = (const float*)d_in[3];   // [D]
    const float* Wv = (const float*)d_in[4];   // [D,D]
    const float* bv = (const float*)d_in[5];   // [D]

    float* outp = (float*)d_out;               // output section [T,B,D]
    float* hsec = outp + TBD;                  // h section [T+1,B,D]

    // k -> output section, v -> h[1:] section: element-exact in-place (safe,
    // see scan comments). No workspace needed for k/v themselves.
    float* kw = outp;
    float* vw = hsec + BD;

    const size_t bf16_bytes = (TBD + 2 * (size_t)D_DIM * D_DIM) * sizeof(short);
    const size_t agg_bytes  = (size_t)NG * BD * sizeof(float2);    // 33.6 MB

    bool bf16_path = false;
    size_t avail = ws_size;
    char* scan_ws = (char*)d_ws;
    if (ws_size >= bf16_bytes) {
        bf16_path = true;
        avail   -= bf16_bytes;
        scan_ws += bf16_bytes;
    }

    // mode 2 = fused-agg single extra read of k/v; 1 = 3-phase; 0 = seq.
    int mode = 0, nc = 0;
    if (bf16_path && avail >= agg_bytes) mode = 2;
    else if (avail >= 3 * (size_t)128 * BD * sizeof(float)) { mode = 1; nc = 128; }
    else if (avail >= 3 * (size_t)32  * BD * sizeof(float)) { mode = 1; nc = 32; }

    if (bf16_path) {
        short* xb  = (short*)d_ws;                       // [T*B, D] bf16
        short* Wkb = xb + TBD;                           // [D, D] bf16
        short* Wvb = Wkb + (size_t)D_DIM * D_DIM;
        cvt_f32_bf16<<<dim3((int)(TBD / 8 / 256)), 256, 0, stream>>>(x, xb, (int)(TBD / 8));
        cvt_f32_bf16<<<dim3(D_DIM * D_DIM / 8 / 256), 256, 0, stream>>>(Wk, Wkb, D_DIM * D_DIM / 8);
        cvt_f32_bf16<<<dim3(D_DIM * D_DIM / 8 / 256), 256, 0, stream>>>(Wv, Wvb, D_DIM * D_DIM / 8);
        if (mode == 2) {
            float2* agg = (float2*)scan_ws;
            gemm_kv_fused<<<dim3(8, 256), 256, 0, stream>>>(
                xb, Wkb, bk, Wvb, bv, kw, vw, agg);
            scan_hinit<<<dim3(BD / 256), 256, 0, stream>>>(h0, agg, hsec);
            scan_apply<<<dim3(BD / 256, NG), 256, 0, stream>>>(kw, vw, agg, outp, hsec);
            return;
        }
        gemm_kv_bf16<<<dim3(8, 256, 2), 256, 0, stream>>>(xb, Wkb, bk, Wvb, bv, kw, vw);
    } else {
        gemm_kv_f32src<<<dim3(8, 256, 2), 256, 0, stream>>>(x, Wk, bk, Wv, bv, kw, vw);
    }

    if (mode == 1) {
        const int tc = T_DIM / nc;
        float* Aab   = (float*)scan_ws;
        float* Bab   = Aab + (size_t)nc * BD;
        float* Hinit = Bab + (size_t)nc * BD;
        scan_phase_a<<<dim3(BD / 256, nc), 256, 0, stream>>>(kw, vw, Aab, Bab, tc);
        scan_phase_b<<<dim3(BD / 256), 256, 0, stream>>>(h0, Aab, Bab, Hinit, hsec, nc);
        scan_phase_c<<<dim3(BD / 256, nc), 256, 0, stream>>>(kw, vw, Hinit, outp, hsec, tc);
    } else {
        scan_kernel<<<dim3(BD / 64), 64, 0, stream>>>(kw, vw, h0, outp, hsec);
    }
}